// Round 4
// baseline (919.796 us; speedup 1.0000x reference)
//
#include <hip/hip_runtime.h>
#include <cstdint>

// N=100000 nodes, E=1.6M edges, D=32, 5D=160, ATTR=33
constexpr int D      = 32;
constexpr int FD     = 160;
constexpr int ATTRD  = 33;
constexpr int WTILE  = 32;    // edges per wave: 32x32x16 MFMA halves B-reads/edge vs 16x16
constexpr int BLOCK  = 256;   // 4 waves/block, wave w -> tile blockIdx*4+w
constexpr int NKS    = 10;    // K-steps of 16 for the 160-K GEMMs
constexpr int NNT    = 5;     // N-tiles of 32
constexpr int ASTR   = 168;   // sA row stride (shorts): 336 B; dword-stride 84 ≡ 20 mod 32
                              // -> b128 reads land 8 lanes per 4-bank group (0 conflicts, R3)
constexpr int SWSTR  = 36;    // sW row stride (floats): 144 B rows, 16B-aligned float4
constexpr int WBYTES = 10752; // per-wave shared = max(32*168*2=10752 sA, 32*36*4=4608 sW)
                              // LDS/block 43008 -> 3 blocks/CU; matches (256,3) reg budget

typedef __attribute__((ext_vector_type(8)))  short short8;  // 8 bf16 (4 VGPRs) MFMA A/B frag
typedef __attribute__((ext_vector_type(16))) float f32x16;  // 32x32 MFMA C/D frag

// 2*log2(e): tanh via exp2 directly (saves the __expf range-scale mul)
#define TWO_LOG2E 2.8853900817779268f
#define LOG2E     1.4426950408889634f

__device__ __forceinline__ float fast_tanh(float x) {
    // 1 - 2/(e^{2x}+1), e^{2x} = exp2(x*2log2e): mul, exp2, add, rcp, fma
    float e = __builtin_amdgcn_exp2f(x * TWO_LOG2E);
    return 1.0f - 2.0f * __builtin_amdgcn_rcpf(e + 1.0f);
}
// packed f32 pair -> 2 bf16 (RNE) in one instruction; lo -> bits[15:0]
__device__ __forceinline__ unsigned cvtpk(float lo, float hi) {
    unsigned r;
    asm("v_cvt_pk_bf16_f32 %0, %1, %2" : "=v"(r) : "v"(lo), "v"(hi));
    return r;
}

// RNE bf16 (host-side packing path kept for prep_weights)
__device__ __forceinline__ unsigned short bf16rne(float x) {
    union { float f; unsigned u; } v; v.f = x;
    unsigned r = v.u + 0x7fffu + ((v.u >> 16) & 1u);
    return (unsigned short)(r >> 16);
}
__device__ __forceinline__ f32x16 zero16() {
    return (f32x16){0.f,0.f,0.f,0.f,0.f,0.f,0.f,0.f,0.f,0.f,0.f,0.f,0.f,0.f,0.f,0.f};
}

// Pack Wd1 (160x160) and W1 rows 0..31 (32x32) into bf16 B-fragment lane order
// for mfma_f32_32x32x16_bf16. B-chunk (nt,ks): lane L holds
// B[ks*16 + (L>>5)*8 + j][nt*32 + (L&31)], j<8.
// ws layout (shorts): [0, 25600) Wd1 frags; [25600, 26624) W1 frags (2 K-steps).
// W1 row 32 is applied as a rank-1 VALU correction in the kernel.
__global__ void prep_weights(const float* __restrict__ Wd1,
                             const float* __restrict__ W1,
                             unsigned short* __restrict__ wsb) {
    int t = blockIdx.x * blockDim.x + threadIdx.x;
    if (t < FD * FD) {
        int k = t / FD, n = t - k * FD;
        int ks = k >> 4, half = (k >> 3) & 1, j = k & 7;
        int nt = n >> 5, col = n & 31;
        int dst = ((nt * NKS + ks) * 64 + half * 32 + col) * 8 + j;
        wsb[dst] = bf16rne(Wd1[t]);
    } else if (t < FD * FD + 32 * D) {
        int t2 = t - FD * FD;            // t2 = k*32 + n, k in [0,32)
        int k = t2 >> 5, n = t2 & 31;
        int ks = k >> 4, half = (k >> 3) & 1, j = k & 7;
        int dst = FD * FD + (ks * 64 + half * 32 + n) * 8 + j;
        wsb[dst] = bf16rne(W1[k * D + n]);
    }
}

// R4: VALU trim + explicit top-of-kernel prefetch. Structure identical to R3
// (32x32x16, 32 edges/wave, no barriers, per-wave LDS, sW/sA alias).
// (256,3): cap 170, live ~160 peak (C 80 + B in flight + Wc 16 + edge regs).
__global__ __launch_bounds__(BLOCK, 3)
void prop_mfma(const float* __restrict__ xn,
               const float* __restrict__ xe_attr,
               const float* __restrict__ W1,
               const float* __restrict__ b1,
               const unsigned short* __restrict__ wsb,
               const int*   __restrict__ esrc,
               const int*   __restrict__ edst,
               float* __restrict__ out,
               int E)
{
    __shared__ __align__(16) unsigned char sMem[4 * WBYTES];   // 43008 B/block

    const int tid  = threadIdx.x;
    const int lane = tid & 63;
    const int w    = tid >> 6;
    const int col  = lane & 31;   // edge / output-column role
    const int half = lane >> 5;   // k-half selector
    unsigned char* wbase = sMem + w * WBYTES;
    float*          sW = reinterpret_cast<float*>(wbase);          // [32][SWSTR] f32
    unsigned short* sA = reinterpret_cast<unsigned short*>(wbase); // [32][ASTR] bf16

    const long tile = (long)blockIdx.x * 4 + w;
    const long e0   = tile * WTILE;
    if (e0 >= (long)E) return;                      // wave-uniform
    const int nv = min(WTILE, (int)((long)E - e0));

    const short8* Bp  = reinterpret_cast<const short8*>(wsb);
    const short8* W1p = reinterpret_cast<const short8*>(wsb + FD * FD);

    // ================ TOP-OF-KERNEL PREFETCH: all per-edge global data =========
    // Lane owns edge e=col (clamped clone for tail). Gather latency hides under
    // fc1's MFMA + silu work. se/de/a32o are shfl-broadcast later per row.
    const int e  = (col < nv) ? col : 0;
    const int ei = (int)e0 + e;
    const int se = esrc[ei], de = edst[ei];
    const float* ar  = xe_attr + (size_t)ei * ATTRD;
    const float* xsp = xn + (size_t)se * D;
    const float* xdp = xn + (size_t)de * D;
    // attr channels for A-frags: k = half*8+j (A0), 16+half*8+j (A1), + col 32
    float arv0[8], arv1[8];
    #pragma unroll
    for (int j = 0; j < 8; ++j) { arv0[j] = ar[half * 8 + j]; arv1[j] = ar[16 + half * 8 + j]; }
    const float a32o = ar[32];
    // xn channels this lane computes in features: {half*8..+8} u {16+half*8..+8}
    float4 xs_a = *reinterpret_cast<const float4*>(xsp + half * 8);
    float4 xs_b = *reinterpret_cast<const float4*>(xsp + half * 8 + 4);
    float4 xs_c = *reinterpret_cast<const float4*>(xsp + 16 + half * 8);
    float4 xs_d = *reinterpret_cast<const float4*>(xsp + 16 + half * 8 + 4);
    float4 xd_a = *reinterpret_cast<const float4*>(xdp + half * 8);
    float4 xd_b = *reinterpret_cast<const float4*>(xdp + half * 8 + 4);
    float4 xd_c = *reinterpret_cast<const float4*>(xdp + 16 + half * 8);
    float4 xd_d = *reinterpret_cast<const float4*>(xdp + 16 + half * 8 + 4);

    // ---------------- fc1: W = silu(attr @ W1 + b1), M=32 ------------------------
    // C/D layout: lane holds col, rows (r&3)+8*(r>>2)+4*half -- kept in Wc
    // (epilogue layout) AND written to sW[row][col] for the features stage.
    f32x16 Wc;
    {
        union { unsigned u[4]; short8 v; } A0, A1;
        #pragma unroll
        for (int p = 0; p < 4; ++p) {
            A0.u[p] = cvtpk(arv0[2 * p], arv0[2 * p + 1]);
            A1.u[p] = cvtpk(arv1[2 * p], arv1[2 * p + 1]);
        }
        f32x16 c = zero16();
        c = __builtin_amdgcn_mfma_f32_32x32x16_bf16(A0.v, W1p[lane],      c, 0, 0, 0);
        c = __builtin_amdgcn_mfma_f32_32x32x16_bf16(A1.v, W1p[64 + lane], c, 0, 0, 0);

        float b1c  = b1[col];
        float w32c = W1[32 * D + col];
        #pragma unroll
        for (int r = 0; r < 16; ++r) {
            int row = (r & 3) + 8 * (r >> 2) + 4 * half;
            float a32 = __shfl(a32o, row, 32);     // edge row's attr[32], no reload
            float x = c[r] + b1c + a32 * w32c;
            float s = x * __builtin_amdgcn_rcpf(1.0f + __builtin_amdgcn_exp2f(-x * LOG2E));
            Wc[r] = s;
            sW[row * SWSTR + col] = s;   // bank (4*row+col)%32: 2 lanes/bank, free
        }
    }

    // ---------------- features: lane owns edge col, 16 channels ------------------
    // wf fully preloaded BEFORE any sA write (sA aliases sW!).
    {
        float4 wfa = *reinterpret_cast<const float4*>(&sW[e * SWSTR + half * 8]);
        float4 wfb = *reinterpret_cast<const float4*>(&sW[e * SWSTR + half * 8 + 4]);
        float4 wfc = *reinterpret_cast<const float4*>(&sW[e * SWSTR + 16 + half * 8]);
        float4 wfd = *reinterpret_cast<const float4*>(&sW[e * SWSTR + 16 + half * 8 + 4]);
        float wf16[16] = {wfa.x,wfa.y,wfa.z,wfa.w, wfb.x,wfb.y,wfb.z,wfb.w,
                          wfc.x,wfc.y,wfc.z,wfc.w, wfd.x,wfd.y,wfd.z,wfd.w};
        float xs16[16] = {xs_a.x,xs_a.y,xs_a.z,xs_a.w, xs_b.x,xs_b.y,xs_b.z,xs_b.w,
                          xs_c.x,xs_c.y,xs_c.z,xs_c.w, xs_d.x,xs_d.y,xs_d.z,xs_d.w};
        float xd16[16] = {xd_a.x,xd_a.y,xd_a.z,xd_a.w, xd_b.x,xd_b.y,xd_b.z,xd_b.w,
                          xd_c.x,xd_c.y,xd_c.z,xd_c.w, xd_d.x,xd_d.y,xd_d.z,xd_d.w};
        #pragma unroll
        for (int p = 0; p < 2; ++p) {
            int cb = p * 16 + half * 8;               // channel base in the edge row
            float g8[8], a8[8];
            #pragma unroll
            for (int c = 0; c < 8; ++c) {
                float wfv = wf16[p * 8 + c];
                g8[c] = wfv * (xs16[p * 8 + c] - xd16[p * 8 + c]);
                a8[c] = wfv * (xs16[p * 8 + c] + xd16[p * 8 + c]) * 0.5f;
            }
            union { unsigned u[4]; short8 v; } T[5];
            #pragma unroll
            for (int q = 0; q < 4; ++q) {
                int c0 = 2 * q, c1 = 2 * q + 1;
                T[0].u[q] = cvtpk(fast_tanh(g8[c0]),         fast_tanh(g8[c1]));
                T[1].u[q] = cvtpk(fast_tanh(a8[c0]),         fast_tanh(a8[c1]));
                T[2].u[q] = cvtpk(fast_tanh(g8[c0]*a8[c0]),  fast_tanh(g8[c1]*a8[c1]));
                T[3].u[q] = cvtpk(fast_tanh(g8[c0]*g8[c0]),  fast_tanh(g8[c1]*g8[c1]));
                T[4].u[q] = cvtpk(fast_tanh(a8[c0]*a8[c0]),  fast_tanh(a8[c1]*a8[c1]));
            }
            #pragma unroll
            for (int f = 0; f < 5; ++f)
                *reinterpret_cast<short8*>(&sA[e * ASTR + f * 32 + cb]) = T[f].v;
        }
    }

    // ---------------- matmul 1: 32 edges x 160 cols ------------------------------
    f32x16 C[NNT];
    #pragma unroll
    for (int t = 0; t < NNT; ++t) C[t] = zero16();
    #pragma unroll
    for (int ks = 0; ks < NKS; ++ks) {
        short8 af = *reinterpret_cast<const short8*>(&sA[col * ASTR + ks * 16 + half * 8]);
        #pragma unroll
        for (int nt = 0; nt < NNT; ++nt)
            C[nt] = __builtin_amdgcn_mfma_f32_32x32x16_bf16(
                af, Bp[(nt * NKS + ks) * 64 + lane], C[nt], 0, 0, 0);
    }

    // ---------------- tv_norm + tanh -> sA (transpose for mm2 A) -----------------
    #pragma unroll
    for (int r = 0; r < 16; ++r) {
        float s = 0.f, q = 0.f;
        #pragma unroll
        for (int nt = 0; nt < NNT; ++nt) { float v = C[nt][r]; s += v; q += v * v; }
        #pragma unroll
        for (int m = 1; m < 32; m <<= 1) { s += __shfl_xor(s, m); q += __shfl_xor(q, m); }
        float mean = s * (1.0f / FD);
        float sc = __builtin_amdgcn_rsqf(q - (float)FD * mean * mean + 1e-3f);
        int row = (r & 3) + 8 * (r >> 2) + 4 * half;
        float t0 = fast_tanh((C[0][r] - mean) * sc);
        float t1 = fast_tanh((C[1][r] - mean) * sc);
        float t2 = fast_tanh((C[2][r] - mean) * sc);
        float t3 = fast_tanh((C[3][r] - mean) * sc);
        float t4 = fast_tanh((C[4][r] - mean) * sc);
        unsigned p01 = cvtpk(t0, t1);
        unsigned p23 = cvtpk(t2, t3);
        unsigned p4  = cvtpk(t4, t4);
        sA[row * ASTR +   0 + col] = (unsigned short)p01;
        sA[row * ASTR +  32 + col] = (unsigned short)(p01 >> 16);  // ds_write_b16_d16_hi
        sA[row * ASTR +  64 + col] = (unsigned short)p23;
        sA[row * ASTR +  96 + col] = (unsigned short)(p23 >> 16);
        sA[row * ASTR + 128 + col] = (unsigned short)p4;
    }

    // ---------------- matmul 2 (A from wave-local LDS) ---------------------------
    #pragma unroll
    for (int t = 0; t < NNT; ++t) C[t] = zero16();
    #pragma unroll
    for (int ks = 0; ks < NKS; ++ks) {
        short8 af = *reinterpret_cast<const short8*>(&sA[col * ASTR + ks * 16 + half * 8]);
        #pragma unroll
        for (int nt = 0; nt < NNT; ++nt)
            C[nt] = __builtin_amdgcn_mfma_f32_32x32x16_bf16(
                af, Bp[(nt * NKS + ks) * 64 + lane], C[nt], 0, 0, 0);
    }

    // ---------------- epilogue: msg = tile(W,5)*tanh; atomics --------------------
    // se/de shfl-broadcast from the owning lane (no reloads). Condition row>=nv
    // and the shfl source lane are uniform within each 32-lane half-group.
    #pragma unroll
    for (int r = 0; r < 16; ++r) {
        int row = (r & 3) + 8 * (r >> 2) + 4 * half;
        if (row >= nv) continue;
        int sd = __shfl(de, row, 32);
        int ss = __shfl(se, row, 32);
        float wv = Wc[r];
        float m0 = fast_tanh(C[0][r]) * wv;
        float A4 = (fast_tanh(C[1][r]) + fast_tanh(C[2][r])
                  + fast_tanh(C[3][r]) + fast_tanh(C[4][r])) * wv;
        atomicAdd(out + (size_t)sd * D + col, m0 + 0.5f * A4);
        atomicAdd(out + (size_t)ss * D + col, 0.5f * A4 - m0);
    }
}

extern "C" void kernel_launch(void* const* d_in, const int* in_sizes, int n_in,
                              void* d_out, int out_size, void* d_ws, size_t ws_size,
                              hipStream_t stream)
{
    const float* xn   = (const float*)d_in[0];
    const float* attr = (const float*)d_in[1];
    const float* W1   = (const float*)d_in[2];
    const float* b1   = (const float*)d_in[3];
    const float* Wd1  = (const float*)d_in[4];
    const int*   esrc = (const int*)d_in[5];
    const int*   edst = (const int*)d_in[6];
    float* out = (float*)d_out;
    unsigned short* wsb = (unsigned short*)d_ws;   // 26624 bf16 packed B-frags

    const int E = in_sizes[5];

    hipMemsetAsync(d_out, 0, (size_t)out_size * sizeof(float), stream);
    prep_weights<<<(FD * FD + 32 * D + 255) / 256, 256, 0, stream>>>(Wd1, W1, wsb);
    const long tiles = ((long)E + WTILE - 1) / WTILE;
    const int grid = (int)((tiles + 3) / 4);
    prop_mfma<<<grid, BLOCK, 0, stream>>>(xn, attr, W1, b1, wsb, esrc, edst, out, E);
}

// Round 5
// 904.833 us; speedup vs baseline: 1.0165x; 1.0165x over previous
//
#include <hip/hip_runtime.h>
#include <cstdint>

// N=100000 nodes, E=1.6M edges, D=32, 5D=160, ATTR=33
constexpr int D      = 32;
constexpr int FD     = 160;
constexpr int ATTRD  = 33;
constexpr int WTILE  = 32;    // edges per wave: 32x32x16 MFMA halves B-reads/edge vs 16x16
constexpr int BLOCK  = 256;   // 4 waves/block, wave w -> tile blockIdx*4+w
constexpr int NKS    = 10;    // K-steps of 16 for the 160-K GEMMs
constexpr int NNT    = 5;     // N-tiles of 32
constexpr int ASTR   = 168;   // sA row stride (shorts): 336 B; dword-stride 84 ≡ 20 mod 32
                              // -> b128 reads land 8 lanes per 4-bank group (0 conflicts, R3)
constexpr int SWSTR  = 36;    // sW row stride (floats): 144 B rows, 16B-aligned float4
constexpr int WBYTES = 10752; // per-wave shared = max(32*168*2=10752 sA, 32*36*4=4608 sW)
                              // LDS/block 43008 -> 3 blocks/CU; matches (256,3) reg budget

typedef __attribute__((ext_vector_type(8)))  short short8;  // 8 bf16 (4 VGPRs) MFMA A/B frag
typedef __attribute__((ext_vector_type(16))) float f32x16;  // 32x32 MFMA C/D frag

#define TWO_LOG2E 2.8853900817779268f
#define LOG2E     1.4426950408889634f

__device__ __forceinline__ float fast_tanh(float x) {
    // 1 - 2/(e^{2x}+1), e^{2x} = exp2(x*2log2e): mul, exp2, add, rcp, fma
    float e = __builtin_amdgcn_exp2f(x * TWO_LOG2E);
    return 1.0f - 2.0f * __builtin_amdgcn_rcpf(e + 1.0f);
}
// packed f32 pair -> 2 bf16 (RNE) in one instruction; lo -> bits[15:0]
__device__ __forceinline__ unsigned cvtpk(float lo, float hi) {
    unsigned r;
    asm("v_cvt_pk_bf16_f32 %0, %1, %2" : "=v"(r) : "v"(lo), "v"(hi));
    return r;
}
// RNE bf16 (prep_weights path)
__device__ __forceinline__ unsigned short bf16rne(float x) {
    union { float f; unsigned u; } v; v.f = x;
    unsigned r = v.u + 0x7fffu + ((v.u >> 16) & 1u);
    return (unsigned short)(r >> 16);
}
__device__ __forceinline__ f32x16 zero16() {
    return (f32x16){0.f,0.f,0.f,0.f,0.f,0.f,0.f,0.f,0.f,0.f,0.f,0.f,0.f,0.f,0.f,0.f};
}

// Pack Wd1 (160x160) and W1 rows 0..31 (32x32) into bf16 B-fragment lane order
// for mfma_f32_32x32x16_bf16. B-chunk (nt,ks): lane L holds
// B[ks*16 + (L>>5)*8 + j][nt*32 + (L&31)], j<8.
// ws layout (shorts): [0, 25600) Wd1 frags; [25600, 26624) W1 frags (2 K-steps).
// W1 row 32 is applied as a rank-1 VALU correction in the kernel.
__global__ void prep_weights(const float* __restrict__ Wd1,
                             const float* __restrict__ W1,
                             unsigned short* __restrict__ wsb) {
    int t = blockIdx.x * blockDim.x + threadIdx.x;
    if (t < FD * FD) {
        int k = t / FD, n = t - k * FD;
        int ks = k >> 4, half = (k >> 3) & 1, j = k & 7;
        int nt = n >> 5, col = n & 31;
        int dst = ((nt * NKS + ks) * 64 + half * 32 + col) * 8 + j;
        wsb[dst] = bf16rne(Wd1[t]);
    } else if (t < FD * FD + 32 * D) {
        int t2 = t - FD * FD;            // t2 = k*32 + n, k in [0,32)
        int k = t2 >> 5, n = t2 & 31;
        int ks = k >> 4, half = (k >> 3) & 1, j = k & 7;
        int dst = FD * FD + (ks * 64 + half * 32 + n) * 8 + j;
        wsb[dst] = bf16rne(W1[k * D + n]);
    }
}

// R5: R3 structure + R4's VALU trims (cvtpk packing, exp2-tanh, shfl-broadcast
// of a32/sd/ss) WITHOUT R4's bulk register prefetch, which spilled ~10 dwords
// per thread (WRITE 400->523MB, dur 589->730). Loads stay where they're used
// (R3 placement); only se/de/a32o (3 regs) persist from the top.
// (256,3): cap 170, peak live ~135 (C 80 + Wc 16 + B-frags in flight + misc).
// No __syncthreads: each wave owns 32 edges end-to-end; LDS per-wave; same-wave
// DS ordering is program order. Alias timeline: fc1 writes sW -> features read
// sW fully (wf preloaded BEFORE any sA write) -> features write sA -> mm1 reads
// sA -> tvnorm overwrites sA -> mm2 reads sA -> epilogue registers only.
__global__ __launch_bounds__(BLOCK, 3)
void prop_mfma(const float* __restrict__ xn,
               const float* __restrict__ xe_attr,
               const float* __restrict__ W1,
               const float* __restrict__ b1,
               const unsigned short* __restrict__ wsb,
               const int*   __restrict__ esrc,
               const int*   __restrict__ edst,
               float* __restrict__ out,
               int E)
{
    __shared__ __align__(16) unsigned char sMem[4 * WBYTES];   // 43008 B/block

    const int tid  = threadIdx.x;
    const int lane = tid & 63;
    const int w    = tid >> 6;
    const int col  = lane & 31;   // edge / output-column role
    const int half = lane >> 5;   // k-half selector
    unsigned char* wbase = sMem + w * WBYTES;
    float*          sW = reinterpret_cast<float*>(wbase);          // [32][SWSTR] f32
    unsigned short* sA = reinterpret_cast<unsigned short*>(wbase); // [32][ASTR] bf16

    const long tile = (long)blockIdx.x * 4 + w;
    const long e0   = tile * WTILE;
    if (e0 >= (long)E) return;                      // wave-uniform
    const int nv = min(WTILE, (int)((long)E - e0));

    const short8* Bp  = reinterpret_cast<const short8*>(wsb);
    const short8* W1p = reinterpret_cast<const short8*>(wsb + FD * FD);

    // Per-edge identity (lane owns edge e=col, clamped clone for tail). Only
    // these 3 values persist to be shfl-broadcast later -- no bulk prefetch.
    const int e  = (col < nv) ? col : 0;
    const int ei = (int)e0 + e;
    const int se = esrc[ei], de = edst[ei];
    const float a32o = xe_attr[(size_t)ei * ATTRD + 32];

    // ---------------- fc1: W = silu(attr @ W1 + b1), M=32 ------------------------
    // C/D layout: lane holds col, rows (r&3)+8*(r>>2)+4*half -- kept in Wc
    // (epilogue layout) AND written to sW[row][col] for the features stage.
    f32x16 Wc;
    {
        const float* ar = xe_attr + (size_t)ei * ATTRD;
        float arv0[8], arv1[8];
        #pragma unroll
        for (int j = 0; j < 8; ++j) {
            arv0[j] = ar[half * 8 + j];
            arv1[j] = ar[16 + half * 8 + j];
        }
        union { unsigned u[4]; short8 v; } A0, A1;
        #pragma unroll
        for (int p = 0; p < 4; ++p) {
            A0.u[p] = cvtpk(arv0[2 * p], arv0[2 * p + 1]);
            A1.u[p] = cvtpk(arv1[2 * p], arv1[2 * p + 1]);
        }
        f32x16 c = zero16();
        c = __builtin_amdgcn_mfma_f32_32x32x16_bf16(A0.v, W1p[lane],      c, 0, 0, 0);
        c = __builtin_amdgcn_mfma_f32_32x32x16_bf16(A1.v, W1p[64 + lane], c, 0, 0, 0);

        float b1c  = b1[col];
        float w32c = W1[32 * D + col];
        #pragma unroll
        for (int r = 0; r < 16; ++r) {
            int row = (r & 3) + 8 * (r >> 2) + 4 * half;
            float a32 = __shfl(a32o, row, 32);     // edge row's attr[32], no reload
            float x = c[r] + b1c + a32 * w32c;
            float s = x * __builtin_amdgcn_rcpf(1.0f + __builtin_amdgcn_exp2f(-x * LOG2E));
            Wc[r] = s;
            sW[row * SWSTR + col] = s;   // bank (4*row+col)%32: 2 lanes/bank, free
        }
    }

    // ---------------- features: lane owns edge col, 16 channels ------------------
    // Channels {half*8..+8} u {16+half*8..+8}; loads placed where used (R3
    // style, lean registers). wf fully preloaded BEFORE any sA write (alias!).
    {
        const float* xsp = xn + (size_t)se * D;
        const float* xdp = xn + (size_t)de * D;
        float4 wfa = *reinterpret_cast<const float4*>(&sW[e * SWSTR + half * 8]);
        float4 wfb = *reinterpret_cast<const float4*>(&sW[e * SWSTR + half * 8 + 4]);
        float4 wfc = *reinterpret_cast<const float4*>(&sW[e * SWSTR + 16 + half * 8]);
        float4 wfd = *reinterpret_cast<const float4*>(&sW[e * SWSTR + 16 + half * 8 + 4]);
        float wf16[16] = {wfa.x,wfa.y,wfa.z,wfa.w, wfb.x,wfb.y,wfb.z,wfb.w,
                          wfc.x,wfc.y,wfc.z,wfc.w, wfd.x,wfd.y,wfd.z,wfd.w};
        #pragma unroll
        for (int p = 0; p < 2; ++p) {
            int cb = p * 16 + half * 8;               // channel base in the edge row
            float4 xsa = *reinterpret_cast<const float4*>(xsp + cb);
            float4 xsb = *reinterpret_cast<const float4*>(xsp + cb + 4);
            float4 xda = *reinterpret_cast<const float4*>(xdp + cb);
            float4 xdb = *reinterpret_cast<const float4*>(xdp + cb + 4);
            float xs8[8] = {xsa.x,xsa.y,xsa.z,xsa.w, xsb.x,xsb.y,xsb.z,xsb.w};
            float xd8[8] = {xda.x,xda.y,xda.z,xda.w, xdb.x,xdb.y,xdb.z,xdb.w};
            float g8[8], a8[8];
            #pragma unroll
            for (int c = 0; c < 8; ++c) {
                float wfv = wf16[p * 8 + c];
                g8[c] = wfv * (xs8[c] - xd8[c]);
                a8[c] = wfv * (xs8[c] + xd8[c]) * 0.5f;
            }
            union { unsigned u[4]; short8 v; } T[5];
            #pragma unroll
            for (int q = 0; q < 4; ++q) {
                int c0 = 2 * q, c1 = 2 * q + 1;
                T[0].u[q] = cvtpk(fast_tanh(g8[c0]),        fast_tanh(g8[c1]));
                T[1].u[q] = cvtpk(fast_tanh(a8[c0]),        fast_tanh(a8[c1]));
                T[2].u[q] = cvtpk(fast_tanh(g8[c0]*a8[c0]), fast_tanh(g8[c1]*a8[c1]));
                T[3].u[q] = cvtpk(fast_tanh(g8[c0]*g8[c0]), fast_tanh(g8[c1]*g8[c1]));
                T[4].u[q] = cvtpk(fast_tanh(a8[c0]*a8[c0]), fast_tanh(a8[c1]*a8[c1]));
            }
            #pragma unroll
            for (int f = 0; f < 5; ++f)
                *reinterpret_cast<short8*>(&sA[e * ASTR + f * 32 + cb]) = T[f].v;
        }
    }

    // ---------------- matmul 1: 32 edges x 160 cols ------------------------------
    // A-frag: one b128 per K-step, amortized over 5 MFMAs. B streams from L2.
    f32x16 C[NNT];
    #pragma unroll
    for (int t = 0; t < NNT; ++t) C[t] = zero16();
    #pragma unroll
    for (int ks = 0; ks < NKS; ++ks) {
        short8 af = *reinterpret_cast<const short8*>(&sA[col * ASTR + ks * 16 + half * 8]);
        #pragma unroll
        for (int nt = 0; nt < NNT; ++nt)
            C[nt] = __builtin_amdgcn_mfma_f32_32x32x16_bf16(
                af, Bp[(nt * NKS + ks) * 64 + lane], C[nt], 0, 0, 0);
    }

    // ---------------- tv_norm + tanh -> sA (transpose for mm2 A) -----------------
    #pragma unroll
    for (int r = 0; r < 16; ++r) {
        float s = 0.f, q = 0.f;
        #pragma unroll
        for (int nt = 0; nt < NNT; ++nt) { float v = C[nt][r]; s += v; q += v * v; }
        #pragma unroll
        for (int m = 1; m < 32; m <<= 1) { s += __shfl_xor(s, m); q += __shfl_xor(q, m); }
        float mean = s * (1.0f / FD);
        float sc = __builtin_amdgcn_rsqf(q - (float)FD * mean * mean + 1e-3f);
        int row = (r & 3) + 8 * (r >> 2) + 4 * half;
        float t0 = fast_tanh((C[0][r] - mean) * sc);
        float t1 = fast_tanh((C[1][r] - mean) * sc);
        float t2 = fast_tanh((C[2][r] - mean) * sc);
        float t3 = fast_tanh((C[3][r] - mean) * sc);
        float t4 = fast_tanh((C[4][r] - mean) * sc);
        unsigned p01 = cvtpk(t0, t1);
        unsigned p23 = cvtpk(t2, t3);
        unsigned p4  = cvtpk(t4, t4);
        sA[row * ASTR +   0 + col] = (unsigned short)p01;
        sA[row * ASTR +  32 + col] = (unsigned short)(p01 >> 16);  // b16_d16_hi store
        sA[row * ASTR +  64 + col] = (unsigned short)p23;
        sA[row * ASTR +  96 + col] = (unsigned short)(p23 >> 16);
        sA[row * ASTR + 128 + col] = (unsigned short)p4;
    }

    // ---------------- matmul 2 (A from wave-local LDS) ---------------------------
    #pragma unroll
    for (int t = 0; t < NNT; ++t) C[t] = zero16();
    #pragma unroll
    for (int ks = 0; ks < NKS; ++ks) {
        short8 af = *reinterpret_cast<const short8*>(&sA[col * ASTR + ks * 16 + half * 8]);
        #pragma unroll
        for (int nt = 0; nt < NNT; ++nt)
            C[nt] = __builtin_amdgcn_mfma_f32_32x32x16_bf16(
                af, Bp[(nt * NKS + ks) * 64 + lane], C[nt], 0, 0, 0);
    }

    // ---------------- epilogue: msg = tile(W,5)*tanh; atomics --------------------
    // se/de shfl-broadcast from the owning lane (no reloads); row>=nv and the
    // shfl source are uniform within each 32-lane half-group.
    #pragma unroll
    for (int r = 0; r < 16; ++r) {
        int row = (r & 3) + 8 * (r >> 2) + 4 * half;
        if (row >= nv) continue;
        int sd = __shfl(de, row, 32);
        int ss = __shfl(se, row, 32);
        float wv = Wc[r];
        float m0 = fast_tanh(C[0][r]) * wv;
        float A4 = (fast_tanh(C[1][r]) + fast_tanh(C[2][r])
                  + fast_tanh(C[3][r]) + fast_tanh(C[4][r])) * wv;
        atomicAdd(out + (size_t)sd * D + col, m0 + 0.5f * A4);
        atomicAdd(out + (size_t)ss * D + col, 0.5f * A4 - m0);
    }
}

extern "C" void kernel_launch(void* const* d_in, const int* in_sizes, int n_in,
                              void* d_out, int out_size, void* d_ws, size_t ws_size,
                              hipStream_t stream)
{
    const float* xn   = (const float*)d_in[0];
    const float* attr = (const float*)d_in[1];
    const float* W1   = (const float*)d_in[2];
    const float* b1   = (const float*)d_in[3];
    const float* Wd1  = (const float*)d_in[4];
    const int*   esrc = (const int*)d_in[5];
    const int*   edst = (const int*)d_in[6];
    float* out = (float*)d_out;
    unsigned short* wsb = (unsigned short*)d_ws;   // 26624 bf16 packed B-frags

    const int E = in_sizes[5];

    hipMemsetAsync(d_out, 0, (size_t)out_size * sizeof(float), stream);
    prep_weights<<<(FD * FD + 32 * D + 255) / 256, 256, 0, stream>>>(Wd1, W1, wsb);
    const long tiles = ((long)E + WTILE - 1) / WTILE;
    const int grid = (int)((tiles + 3) / 4);
    prop_mfma<<<grid, BLOCK, 0, stream>>>(xn, attr, W1, b1, wsb, esrc, edst, out, E);
}